// Round 7
// baseline (303.866 us; speedup 1.0000x reference)
//
#include <hip/hip_runtime.h>

// ---------------------------------------------------------------------------
// Compile-time Clebsch-Gordan / real-basis Wigner-3j generation (exact port of
// the Python reference: _cg_coef, _su2_cg, _q, _w3j, normalization, pw).
// ---------------------------------------------------------------------------

struct W3JT { double v[9][9][9]; };

constexpr double dfact(int n) { double r = 1.0; for (int i = 2; i <= n; ++i) r *= (double)i; return r; }

constexpr double csqrt(double x) {
  if (x <= 0.0) return 0.0;
  double g = x > 1.0 ? x : 1.0;
  for (int i = 0; i < 80; ++i) g = 0.5 * (g + x / g);
  return g;
}

constexpr double cg_coef(int j1, int m1, int j2, int m2, int j3, int m3) {
  if (m1 + m2 != m3) return 0.0;
  int vmin = 0;
  if (j2 - j3 - m1 > vmin) vmin = j2 - j3 - m1;
  if (j1 - j3 + m2 > vmin) vmin = j1 - j3 + m2;
  int vmax = j1 + j2 - j3;
  if (j1 - m1 < vmax) vmax = j1 - m1;
  if (j2 + m2 < vmax) vmax = j2 + m2;
  double pref = csqrt((2.0 * j3 + 1.0) * dfact(j3 + j1 - j2) * dfact(j3 - j1 + j2) * dfact(j1 + j2 - j3) / dfact(j1 + j2 + j3 + 1));
  pref *= csqrt(dfact(j3 + m3) * dfact(j3 - m3) * dfact(j1 + m1) * dfact(j1 - m1) * dfact(j2 + m2) * dfact(j2 - m2));
  double s = 0.0;
  for (int v = vmin; v <= vmax; ++v) {
    double t = 1.0 / (dfact(v) * dfact(j1 + j2 - j3 - v) * dfact(j1 - m1 - v) * dfact(j2 + m2 - v) * dfact(j3 - j2 + m1 + v) * dfact(j3 - j1 - m2 + v));
    s += (v & 1) ? -t : t;
  }
  return pref * s;
}

// Nonzero rows of column `col` of the complex->real change-of-basis matrix
// q(l) (each column has <=2 nonzeros), with the (-i)^l phase applied.
struct QCol { int n; int row[2]; double re[2]; double im[2]; };

constexpr QCol qcol(int l, int col) {
  QCol q{};
  const int lm = l & 3;
  const double pr = (lm == 0) ? 1.0 : (lm == 2) ? -1.0 : 0.0;   // Re((-i)^l)
  const double pi = (lm == 1) ? -1.0 : (lm == 3) ? 1.0 : 0.0;   // Im((-i)^l)
  const int mu = col - l;
  const int am = mu < 0 ? -mu : mu;
  const double is2 = 0.70710678118654752440;
  if (mu == 0) {
    q.n = 1; q.row[0] = l;
    q.re[0] = pr; q.im[0] = pi;
  } else {
    const double s = (am & 1) ? -1.0 : 1.0;   // (-1)^|m|
    double a0 = 0.0, b0 = 0.0, a1 = 0.0, b1 = 0.0;
    if (mu > 0) { a0 = is2; b0 = 0.0;  a1 = s * is2; b1 = 0.0; }      // col l+|m|
    else        { a0 = 0.0; b0 = -is2; a1 = 0.0;     b1 = s * is2; }  // col l-|m|
    q.n = 2;
    q.row[0] = l - am; q.row[1] = l + am;
    q.re[0] = a0 * pr - b0 * pi; q.im[0] = a0 * pi + b0 * pr;
    q.re[1] = a1 * pr - b1 * pi; q.im[1] = a1 * pi + b1 * pr;
  }
  return q;
}

constexpr W3JT make_w3j(int l1, int l2, int l3) {
  W3JT R{};
  double C[9][9][9]{};
  for (int m1 = -l1; m1 <= l1; ++m1)
    for (int m2 = -l2; m2 <= l2; ++m2) {
      int m3 = m1 + m2;
      if (m3 >= -l3 && m3 <= l3)
        C[l1 + m1][l2 + m2][l3 + m3] = cg_coef(l1, m1, l2, m2, l3, m3);
    }
  // C_real[j][l][m] = Re( sum q1[i][j] q2[k][l] conj(q3[n][m]) C[i][k][n] )
  double nrm = 0.0;
  for (int j = 0; j < 2 * l1 + 1; ++j) {
    QCol q1 = qcol(l1, j);
    for (int l = 0; l < 2 * l2 + 1; ++l) {
      QCol q2 = qcol(l2, l);
      for (int m = 0; m < 2 * l3 + 1; ++m) {
        QCol q3 = qcol(l3, m);
        double re = 0.0;
        for (int a = 0; a < q1.n; ++a)
          for (int b = 0; b < q2.n; ++b)
            for (int c = 0; c < q3.n; ++c) {
              double cv = C[q1.row[a]][q2.row[b]][q3.row[c]];
              if (cv == 0.0) continue;
              double ar = q1.re[a], ai = q1.im[a];
              double br = q2.re[b], bi = q2.im[b];
              double cr = q3.re[c], ci = -q3.im[c];   // conj
              double abr = ar * br - ai * bi;
              double abi = ar * bi + ai * br;
              double prr = abr * cr - abi * ci;       // Re(triple product)
              re += prr * cv;
            }
        R.v[j][l][m] = re;
        nrm += re * re;
      }
    }
  }
  double n = csqrt(nrm);
  if (n > 0.0)
    for (int j = 0; j < 2 * l1 + 1; ++j)
      for (int l = 0; l < 2 * l2 + 1; ++l)
        for (int m = 0; m < 2 * l3 + 1; ++m)
          R.v[j][l][m] /= n;
  return R;
}

// instruction counts per output-l (verified against the reference enumeration)
// INS1  = instructions(3,3,4): c-counts {4,6,7,6,4}
// INS21 = instructions(3,4,3): c-counts {4,7,8,8}   (INS22 identical)
constexpr int CNT1[5] = {4, 6, 7, 6, 4};
constexpr int CNT2[4] = {4, 7, 8, 8};

#define NZCHK(V) ((V) > 1e-12 || (V) < -1e-12)

// mid[c*c+k] += w1[IDX] * pw * sum_ij W3J[i][j][k] * xm[a*a+i] * ym[b*b+j]
#define TP_MID(IDX, A, B, C) do { \
  constexpr W3JT T = make_w3j(A, B, C); \
  constexpr double PW = csqrt((2.0 * (C) + 1.0) / (double)CNT1[(C)]); \
  const float wi = w1p[IDX]; \
  float u[2 * (A) + 1]; \
  _Pragma("unroll") for (int i = 0; i < 2 * (A) + 1; ++i) u[i] = wi * xm[(A) * (A) + i]; \
  _Pragma("unroll") for (int i = 0; i < 2 * (A) + 1; ++i) { \
    _Pragma("unroll") for (int j = 0; j < 2 * (B) + 1; ++j) { \
      const float p_ = u[i] * ym[(B) * (B) + j]; \
      _Pragma("unroll") for (int k = 0; k < 2 * (C) + 1; ++k) { \
        if (NZCHK(T.v[i][j][k])) \
          mid[(C) * (C) + k] = __builtin_fmaf((float)(T.v[i][j][k] * PW), p_, mid[(C) * (C) + k]); \
      } \
    } \
  } \
} while (0)

// tv[c*c+k] += pw * sum_ij W3J[i][j][k] * (w21[IDX]*xm_i + w22[IDX]*ym_i) * mid_j
#define TP_OUT(IDX, A, B, C) do { \
  constexpr W3JT T = make_w3j(A, B, C); \
  constexpr double PW = csqrt((2.0 * (C) + 1.0) / (double)CNT2[(C)]); \
  const float wa = w21p[IDX]; \
  const float wb = w22p[IDX]; \
  float u[2 * (A) + 1]; \
  _Pragma("unroll") for (int i = 0; i < 2 * (A) + 1; ++i) \
    u[i] = wa * xm[(A) * (A) + i] + wb * ym[(A) * (A) + i]; \
  _Pragma("unroll") for (int i = 0; i < 2 * (A) + 1; ++i) { \
    _Pragma("unroll") for (int j = 0; j < 2 * (B) + 1; ++j) { \
      const float p_ = u[i] * mid[(B) * (B) + j]; \
      _Pragma("unroll") for (int k = 0; k < 2 * (C) + 1; ++k) { \
        if (NZCHK(T.v[i][j][k])) \
          tv[(C) * (C) + k] = __builtin_fmaf((float)(T.v[i][j][k] * PW), p_, tv[(C) * (C) + k]); \
      } \
    } \
  } \
} while (0)

// ---------------------------------------------------------------------------
// v7: barrier-free streaming, one wave = 16 edges, load k = edge k.
//   Lane l covers float4 slot l of each edge -> EVERY global load/store
//   instruction is one contiguous 1 KB block (8 full cache lines).
//   phase A: stream x,y; per-(edge,lane) hsum only (no payload registers);
//            2 quad shuffles -> row means -> LDS (stride-17).
//   chain  : lanes 0..15, one edge per lane, constant-folded CG chain from
//            LDS means; tv -> LDS. Wave-internal LDS dependences are ordered
//            by the compiler via lgkmcnt (no __syncthreads anywhere).
//   phase B: RE-READ x,y (reuse distance ~ the chain -> L3-resident; input
//            lines are clean so no writeback cost), out = x+y+tv[row].
//            x/y passed twice via distinct __restrict__ params so the
//            compiler cannot CSE phase-B loads into a register hoard; the
//            loads are independent of the chain and can hoist under it.
// ---------------------------------------------------------------------------
__global__ __launch_bounds__(256) void cg2_v7(
    const float4* __restrict__ x4a, const float4* __restrict__ y4a,
    const float4* __restrict__ x4b, const float4* __restrict__ y4b,
    const float* __restrict__ w1p, const float* __restrict__ w21p,
    const float* __restrict__ w22p, float4* __restrict__ o4, int E)
{
  __shared__ float smx[4][16 * 17];
  __shared__ float smy[4][16 * 17];
  __shared__ float smt[4][16 * 17];

  const int wid = threadIdx.x >> 6;            // wave in block
  const int l   = threadIdx.x & 63;            // lane
  const int W   = blockIdx.x * 4 + wid;        // global wave id
  const int e0  = W * 16;                      // first edge of this wave
  const int base = W * 1024 + l;               // float4 index of lane slot
  const int g = l & 3, r = l >> 2;             // chunk, row of lane's slot

  // ---- phase A: contiguous streaming loads, per-edge horizontal sums ----
  float pxk[16], pyk[16];
#pragma unroll
  for (int k = 0; k < 16; ++k) {
    if (e0 + k < E) {
      const float4 xv = x4a[base + 64 * k];
      const float4 yv = y4a[base + 64 * k];
      pxk[k] = (xv.x + xv.y) + (xv.z + xv.w);
      pyk[k] = (yv.x + yv.y) + (yv.z + yv.w);
    } else { pxk[k] = 0.f; pyk[k] = 0.f; }
  }

  // quad butterflies: all 4 lanes of quad r get rowsum(edge k, row r)
#pragma unroll
  for (int k = 0; k < 16; ++k) {
    float rx = pxk[k] + __shfl_xor(pxk[k], 1);
    rx += __shfl_xor(rx, 2);
    float ry = pyk[k] + __shfl_xor(pyk[k], 1);
    ry += __shfl_xor(ry, 2);
    pxk[k] = rx * (1.0f / 16.0f);
    pyk[k] = ry * (1.0f / 16.0f);
  }

  // LDS means: lane (g,r) writes edges k = g, g+4, g+8, g+12 at row r
#pragma unroll
  for (int j = 0; j < 4; ++j) {
    const int k = 4 * j + g;
    smx[wid][k * 17 + r] = pxk[k];
    smy[wid][k * 17 + r] = pyk[k];
  }

  // ---- chain: lanes 0..15, one edge per lane (compiler orders LDS deps) ----
  if (l < 16) {
    const int q = l;
    float xm[16], ym[16];
#pragma unroll
    for (int j = 0; j < 16; ++j) xm[j] = smx[wid][q * 17 + j];
#pragma unroll
    for (int j = 0; j < 16; ++j) ym[j] = smy[wid][q * 17 + j];

    float mid[25];
#pragma unroll
    for (int k = 0; k < 25; ++k) mid[k] = 0.f;

    // INS1 = instructions(3,3,4), reference order
    TP_MID( 0, 0, 0, 0);
    TP_MID( 1, 0, 1, 1);
    TP_MID( 2, 0, 2, 2);
    TP_MID( 3, 0, 3, 3);
    TP_MID( 4, 1, 0, 1);
    TP_MID( 5, 1, 1, 0);
    TP_MID( 6, 1, 1, 2);
    TP_MID( 7, 1, 2, 1);
    TP_MID( 8, 1, 2, 3);
    TP_MID( 9, 1, 3, 2);
    TP_MID(10, 1, 3, 4);
    TP_MID(11, 2, 0, 2);
    TP_MID(12, 2, 1, 1);
    TP_MID(13, 2, 1, 3);
    TP_MID(14, 2, 2, 0);
    TP_MID(15, 2, 2, 2);
    TP_MID(16, 2, 2, 4);
    TP_MID(17, 2, 3, 1);
    TP_MID(18, 2, 3, 3);
    TP_MID(19, 3, 0, 3);
    TP_MID(20, 3, 1, 2);
    TP_MID(21, 3, 1, 4);
    TP_MID(22, 3, 2, 1);
    TP_MID(23, 3, 2, 3);
    TP_MID(24, 3, 3, 0);
    TP_MID(25, 3, 3, 2);
    TP_MID(26, 3, 3, 4);

    float tv[16];
#pragma unroll
    for (int k = 0; k < 16; ++k) tv[k] = 0.f;

    // INS21 == INS22 = instructions(3,4,3); fused via u = w21*xm + w22*ym
    TP_OUT( 0, 0, 0, 0);
    TP_OUT( 1, 0, 1, 1);
    TP_OUT( 2, 0, 2, 2);
    TP_OUT( 3, 0, 3, 3);
    TP_OUT( 4, 1, 0, 1);
    TP_OUT( 5, 1, 1, 0);
    TP_OUT( 6, 1, 1, 2);
    TP_OUT( 7, 1, 2, 1);
    TP_OUT( 8, 1, 2, 3);
    TP_OUT( 9, 1, 3, 2);
    TP_OUT(10, 1, 4, 3);
    TP_OUT(11, 2, 0, 2);
    TP_OUT(12, 2, 1, 1);
    TP_OUT(13, 2, 1, 3);
    TP_OUT(14, 2, 2, 0);
    TP_OUT(15, 2, 2, 2);
    TP_OUT(16, 2, 3, 1);
    TP_OUT(17, 2, 3, 3);
    TP_OUT(18, 2, 4, 2);
    TP_OUT(19, 3, 0, 3);
    TP_OUT(20, 3, 1, 2);
    TP_OUT(21, 3, 2, 1);
    TP_OUT(22, 3, 2, 3);
    TP_OUT(23, 3, 3, 0);
    TP_OUT(24, 3, 3, 2);
    TP_OUT(25, 3, 4, 1);
    TP_OUT(26, 3, 4, 3);

#pragma unroll
    for (int k = 0; k < 16; ++k) smt[wid][q * 17 + k] = tv[k];
  }

  // ---- phase B: re-read x,y (cache-hot), add tv, contiguous store ----
#pragma unroll
  for (int k = 0; k < 16; ++k) {
    if (e0 + k < E) {
      const float4 xv = x4b[base + 64 * k];
      const float4 yv = y4b[base + 64 * k];
      const float t = smt[wid][k * 17 + r];
      float4 o;
      o.x = xv.x + yv.x + t;
      o.y = xv.y + yv.y + t;
      o.z = xv.z + yv.z + t;
      o.w = xv.w + yv.w + t;
      o4[base + 64 * k] = o;
    }
  }
}

extern "C" void kernel_launch(void* const* d_in, const int* in_sizes, int n_in,
                              void* d_out, int out_size, void* d_ws, size_t ws_size,
                              hipStream_t stream) {
  const float4* x4 = (const float4*)d_in[0];
  const float4* y4 = (const float4*)d_in[1];
  const float* w1p = (const float*)d_in[2];
  const float* w21p = (const float*)d_in[3];
  const float* w22p = (const float*)d_in[4];
  float4* o4 = (float4*)d_out;

  const int E = in_sizes[0] / 256;          // (E, 16, 16) fp32
  const int block = 256;                    // 4 waves = 64 edges per block
  const int grid = (E + 63) / 64;

  cg2_v7<<<grid, block, 0, stream>>>(x4, y4, x4, y4, w1p, w21p, w22p, o4, E);
}

// Round 8
// 185.386 us; speedup vs baseline: 1.6391x; 1.6391x over previous
//
#include <hip/hip_runtime.h>

// ---------------------------------------------------------------------------
// Compile-time Clebsch-Gordan / real-basis Wigner-3j generation (exact port of
// the Python reference: _cg_coef, _su2_cg, _q, _w3j, normalization, pw).
// ---------------------------------------------------------------------------

struct W3JT { double v[9][9][9]; };

constexpr double dfact(int n) { double r = 1.0; for (int i = 2; i <= n; ++i) r *= (double)i; return r; }

constexpr double csqrt(double x) {
  if (x <= 0.0) return 0.0;
  double g = x > 1.0 ? x : 1.0;
  for (int i = 0; i < 80; ++i) g = 0.5 * (g + x / g);
  return g;
}

constexpr double cg_coef(int j1, int m1, int j2, int m2, int j3, int m3) {
  if (m1 + m2 != m3) return 0.0;
  int vmin = 0;
  if (j2 - j3 - m1 > vmin) vmin = j2 - j3 - m1;
  if (j1 - j3 + m2 > vmin) vmin = j1 - j3 + m2;
  int vmax = j1 + j2 - j3;
  if (j1 - m1 < vmax) vmax = j1 - m1;
  if (j2 + m2 < vmax) vmax = j2 + m2;
  double pref = csqrt((2.0 * j3 + 1.0) * dfact(j3 + j1 - j2) * dfact(j3 - j1 + j2) * dfact(j1 + j2 - j3) / dfact(j1 + j2 + j3 + 1));
  pref *= csqrt(dfact(j3 + m3) * dfact(j3 - m3) * dfact(j1 + m1) * dfact(j1 - m1) * dfact(j2 + m2) * dfact(j2 - m2));
  double s = 0.0;
  for (int v = vmin; v <= vmax; ++v) {
    double t = 1.0 / (dfact(v) * dfact(j1 + j2 - j3 - v) * dfact(j1 - m1 - v) * dfact(j2 + m2 - v) * dfact(j3 - j2 + m1 + v) * dfact(j3 - j1 - m2 + v));
    s += (v & 1) ? -t : t;
  }
  return pref * s;
}

// Nonzero rows of column `col` of the complex->real change-of-basis matrix
// q(l) (each column has <=2 nonzeros), with the (-i)^l phase applied.
struct QCol { int n; int row[2]; double re[2]; double im[2]; };

constexpr QCol qcol(int l, int col) {
  QCol q{};
  const int lm = l & 3;
  const double pr = (lm == 0) ? 1.0 : (lm == 2) ? -1.0 : 0.0;   // Re((-i)^l)
  const double pi = (lm == 1) ? -1.0 : (lm == 3) ? 1.0 : 0.0;   // Im((-i)^l)
  const int mu = col - l;
  const int am = mu < 0 ? -mu : mu;
  const double is2 = 0.70710678118654752440;
  if (mu == 0) {
    q.n = 1; q.row[0] = l;
    q.re[0] = pr; q.im[0] = pi;
  } else {
    const double s = (am & 1) ? -1.0 : 1.0;   // (-1)^|m|
    double a0 = 0.0, b0 = 0.0, a1 = 0.0, b1 = 0.0;
    if (mu > 0) { a0 = is2; b0 = 0.0;  a1 = s * is2; b1 = 0.0; }      // col l+|m|
    else        { a0 = 0.0; b0 = -is2; a1 = 0.0;     b1 = s * is2; }  // col l-|m|
    q.n = 2;
    q.row[0] = l - am; q.row[1] = l + am;
    q.re[0] = a0 * pr - b0 * pi; q.im[0] = a0 * pi + b0 * pr;
    q.re[1] = a1 * pr - b1 * pi; q.im[1] = a1 * pi + b1 * pr;
  }
  return q;
}

constexpr W3JT make_w3j(int l1, int l2, int l3) {
  W3JT R{};
  double C[9][9][9]{};
  for (int m1 = -l1; m1 <= l1; ++m1)
    for (int m2 = -l2; m2 <= l2; ++m2) {
      int m3 = m1 + m2;
      if (m3 >= -l3 && m3 <= l3)
        C[l1 + m1][l2 + m2][l3 + m3] = cg_coef(l1, m1, l2, m2, l3, m3);
    }
  // C_real[j][l][m] = Re( sum q1[i][j] q2[k][l] conj(q3[n][m]) C[i][k][n] )
  double nrm = 0.0;
  for (int j = 0; j < 2 * l1 + 1; ++j) {
    QCol q1 = qcol(l1, j);
    for (int l = 0; l < 2 * l2 + 1; ++l) {
      QCol q2 = qcol(l2, l);
      for (int m = 0; m < 2 * l3 + 1; ++m) {
        QCol q3 = qcol(l3, m);
        double re = 0.0;
        for (int a = 0; a < q1.n; ++a)
          for (int b = 0; b < q2.n; ++b)
            for (int c = 0; c < q3.n; ++c) {
              double cv = C[q1.row[a]][q2.row[b]][q3.row[c]];
              if (cv == 0.0) continue;
              double ar = q1.re[a], ai = q1.im[a];
              double br = q2.re[b], bi = q2.im[b];
              double cr = q3.re[c], ci = -q3.im[c];   // conj
              double abr = ar * br - ai * bi;
              double abi = ar * bi + ai * br;
              double prr = abr * cr - abi * ci;       // Re(triple product)
              re += prr * cv;
            }
        R.v[j][l][m] = re;
        nrm += re * re;
      }
    }
  }
  double n = csqrt(nrm);
  if (n > 0.0)
    for (int j = 0; j < 2 * l1 + 1; ++j)
      for (int l = 0; l < 2 * l2 + 1; ++l)
        for (int m = 0; m < 2 * l3 + 1; ++m)
          R.v[j][l][m] /= n;
  return R;
}

// instruction counts per output-l (verified against the reference enumeration)
// INS1  = instructions(3,3,4): c-counts {4,6,7,6,4}
// INS21 = instructions(3,4,3): c-counts {4,7,8,8}   (INS22 identical)
constexpr int CNT1[5] = {4, 6, 7, 6, 4};
constexpr int CNT2[4] = {4, 7, 8, 8};

#define NZCHK(V) ((V) > 1e-12 || (V) < -1e-12)

// mid[c*c+k] += w1[IDX] * pw * sum_ij W3J[i][j][k] * xm[a*a+i] * ym[b*b+j]
#define TP_MID(IDX, A, B, C) do { \
  constexpr W3JT T = make_w3j(A, B, C); \
  constexpr double PW = csqrt((2.0 * (C) + 1.0) / (double)CNT1[(C)]); \
  const float wi = w1p[IDX]; \
  float u[2 * (A) + 1]; \
  _Pragma("unroll") for (int i = 0; i < 2 * (A) + 1; ++i) u[i] = wi * xm[(A) * (A) + i]; \
  _Pragma("unroll") for (int i = 0; i < 2 * (A) + 1; ++i) { \
    _Pragma("unroll") for (int j = 0; j < 2 * (B) + 1; ++j) { \
      const float p_ = u[i] * ym[(B) * (B) + j]; \
      _Pragma("unroll") for (int k = 0; k < 2 * (C) + 1; ++k) { \
        if (NZCHK(T.v[i][j][k])) \
          mid[(C) * (C) + k] = __builtin_fmaf((float)(T.v[i][j][k] * PW), p_, mid[(C) * (C) + k]); \
      } \
    } \
  } \
} while (0)

// tv[c*c+k] += pw * sum_ij W3J[i][j][k] * (w21[IDX]*xm_i + w22[IDX]*ym_i) * mid_j
#define TP_OUT(IDX, A, B, C) do { \
  constexpr W3JT T = make_w3j(A, B, C); \
  constexpr double PW = csqrt((2.0 * (C) + 1.0) / (double)CNT2[(C)]); \
  const float wa = w21p[IDX]; \
  const float wb = w22p[IDX]; \
  float u[2 * (A) + 1]; \
  _Pragma("unroll") for (int i = 0; i < 2 * (A) + 1; ++i) \
    u[i] = wa * xm[(A) * (A) + i] + wb * ym[(A) * (A) + i]; \
  _Pragma("unroll") for (int i = 0; i < 2 * (A) + 1; ++i) { \
    _Pragma("unroll") for (int j = 0; j < 2 * (B) + 1; ++j) { \
      const float p_ = u[i] * mid[(B) * (B) + j]; \
      _Pragma("unroll") for (int k = 0; k < 2 * (C) + 1; ++k) { \
        if (NZCHK(T.v[i][j][k])) \
          tv[(C) * (C) + k] = __builtin_fmaf((float)(T.v[i][j][k] * PW), p_, tv[(C) * (C) + k]); \
      } \
    } \
  } \
} while (0)

// ---------------------------------------------------------------------------
// v9: barrier-free autonomous waves, hold-s. Wave = 16 edges, 4 lanes/edge
// (v6 addressing: lane g covers float4 slot 4k+g of its edge -> coalesced).
//   phase 1: 32 loads, s=x+y in regs, per-lane row partials written FLAT to
//            wave-private LDS as 4x ds_write_b128 (no shuffles, no deps).
//   chain  : lanes 0..15, one edge per lane: reduce 4 partials/row from LDS
//            (b128 reads), run constant-folded CG chain, tv -> LDS.
//   phase 3: out = s + tv[row], single store.
// ZERO __syncthreads: all LDS producer->consumer pairs are within one wave
// (wave-synchronous lockstep + compiler lgkmcnt ordering).
// E = 200000 is divisible by 64, so guards never fire (kept for safety).
// ---------------------------------------------------------------------------
typedef float f32x4 __attribute__((ext_vector_type(4)));

__global__ __launch_bounds__(256) void cg2_v9(
    const float4* __restrict__ x4, const float4* __restrict__ y4,
    const float* __restrict__ w1p, const float* __restrict__ w21p,
    const float* __restrict__ w22p, float4* __restrict__ o4, int E)
{
  // per-wave regions; stride per edge = 68 floats (4 chunks x 16 rows + pad)
  __shared__ __align__(16) float spx[4][16 * 68];
  __shared__ __align__(16) float spy[4][16 * 68];
  __shared__ float stv[4][16 * 17];

  const int wid = threadIdx.x >> 6;        // wave in block
  const int l   = threadIdx.x & 63;        // lane
  const int e16 = l >> 2;                  // edge within wave 0..15
  const int g   = l & 3;                   // chunk
  const int e   = blockIdx.x * 64 + wid * 16 + e16;
  const bool ok = (e < E);
  const int base = e * 64 + g;             // float4 index

  float* const px_w = &spx[wid][0];
  float* const py_w = &spy[wid][0];
  float* const tv_w = &stv[wid][0];

  // ---- phase 1: loads, s in regs, flat row-partials ----
  float4 s[16];
  float px[16], py[16];
  if (ok) {
#pragma unroll
    for (int k = 0; k < 16; ++k) {
      const float4 xv = x4[base + 4 * k];
      const float4 yv = y4[base + 4 * k];
      s[k].x = xv.x + yv.x; s[k].y = xv.y + yv.y;
      s[k].z = xv.z + yv.z; s[k].w = xv.w + yv.w;
      px[k] = (xv.x + xv.y) + (xv.z + xv.w);
      py[k] = (yv.x + yv.y) + (yv.z + yv.w);
    }
  } else {
#pragma unroll
    for (int k = 0; k < 16; ++k) { px[k] = 0.f; py[k] = 0.f; }
  }

  // flat transpose: lane (e16,g) writes partials for rows 0..15 contiguously
  {
    const int o = e16 * 68 + g * 16;
#pragma unroll
    for (int j = 0; j < 4; ++j) {
      f32x4 vx = { px[4 * j], px[4 * j + 1], px[4 * j + 2], px[4 * j + 3] };
      f32x4 vy = { py[4 * j], py[4 * j + 1], py[4 * j + 2], py[4 * j + 3] };
      *(f32x4*)&px_w[o + 4 * j] = vx;
      *(f32x4*)&py_w[o + 4 * j] = vy;
    }
  }

  // ---- chain: lanes 0..15, one edge per lane (wave-synchronous) ----
  if (l < 16) {
    const int q = l;
    float xm[16], ym[16];
#pragma unroll
    for (int j = 0; j < 4; ++j) {
      const int o = q * 68 + 4 * j;
      const f32x4 a0 = *(const f32x4*)&px_w[o];
      const f32x4 a1 = *(const f32x4*)&px_w[o + 16];
      const f32x4 a2 = *(const f32x4*)&px_w[o + 32];
      const f32x4 a3 = *(const f32x4*)&px_w[o + 48];
      xm[4 * j + 0] = ((a0.x + a1.x) + (a2.x + a3.x)) * (1.0f / 16.0f);
      xm[4 * j + 1] = ((a0.y + a1.y) + (a2.y + a3.y)) * (1.0f / 16.0f);
      xm[4 * j + 2] = ((a0.z + a1.z) + (a2.z + a3.z)) * (1.0f / 16.0f);
      xm[4 * j + 3] = ((a0.w + a1.w) + (a2.w + a3.w)) * (1.0f / 16.0f);
      const f32x4 b0 = *(const f32x4*)&py_w[o];
      const f32x4 b1 = *(const f32x4*)&py_w[o + 16];
      const f32x4 b2 = *(const f32x4*)&py_w[o + 32];
      const f32x4 b3 = *(const f32x4*)&py_w[o + 48];
      ym[4 * j + 0] = ((b0.x + b1.x) + (b2.x + b3.x)) * (1.0f / 16.0f);
      ym[4 * j + 1] = ((b0.y + b1.y) + (b2.y + b3.y)) * (1.0f / 16.0f);
      ym[4 * j + 2] = ((b0.z + b1.z) + (b2.z + b3.z)) * (1.0f / 16.0f);
      ym[4 * j + 3] = ((b0.w + b1.w) + (b2.w + b3.w)) * (1.0f / 16.0f);
    }

    float mid[25];
#pragma unroll
    for (int k = 0; k < 25; ++k) mid[k] = 0.f;

    // INS1 = instructions(3,3,4), reference order
    TP_MID( 0, 0, 0, 0);
    TP_MID( 1, 0, 1, 1);
    TP_MID( 2, 0, 2, 2);
    TP_MID( 3, 0, 3, 3);
    TP_MID( 4, 1, 0, 1);
    TP_MID( 5, 1, 1, 0);
    TP_MID( 6, 1, 1, 2);
    TP_MID( 7, 1, 2, 1);
    TP_MID( 8, 1, 2, 3);
    TP_MID( 9, 1, 3, 2);
    TP_MID(10, 1, 3, 4);
    TP_MID(11, 2, 0, 2);
    TP_MID(12, 2, 1, 1);
    TP_MID(13, 2, 1, 3);
    TP_MID(14, 2, 2, 0);
    TP_MID(15, 2, 2, 2);
    TP_MID(16, 2, 2, 4);
    TP_MID(17, 2, 3, 1);
    TP_MID(18, 2, 3, 3);
    TP_MID(19, 3, 0, 3);
    TP_MID(20, 3, 1, 2);
    TP_MID(21, 3, 1, 4);
    TP_MID(22, 3, 2, 1);
    TP_MID(23, 3, 2, 3);
    TP_MID(24, 3, 3, 0);
    TP_MID(25, 3, 3, 2);
    TP_MID(26, 3, 3, 4);

    float tv[16];
#pragma unroll
    for (int k = 0; k < 16; ++k) tv[k] = 0.f;

    // INS21 == INS22 = instructions(3,4,3); fused via u = w21*xm + w22*ym
    TP_OUT( 0, 0, 0, 0);
    TP_OUT( 1, 0, 1, 1);
    TP_OUT( 2, 0, 2, 2);
    TP_OUT( 3, 0, 3, 3);
    TP_OUT( 4, 1, 0, 1);
    TP_OUT( 5, 1, 1, 0);
    TP_OUT( 6, 1, 1, 2);
    TP_OUT( 7, 1, 2, 1);
    TP_OUT( 8, 1, 2, 3);
    TP_OUT( 9, 1, 3, 2);
    TP_OUT(10, 1, 4, 3);
    TP_OUT(11, 2, 0, 2);
    TP_OUT(12, 2, 1, 1);
    TP_OUT(13, 2, 1, 3);
    TP_OUT(14, 2, 2, 0);
    TP_OUT(15, 2, 2, 2);
    TP_OUT(16, 2, 3, 1);
    TP_OUT(17, 2, 3, 3);
    TP_OUT(18, 2, 4, 2);
    TP_OUT(19, 3, 0, 3);
    TP_OUT(20, 3, 1, 2);
    TP_OUT(21, 3, 2, 1);
    TP_OUT(22, 3, 2, 3);
    TP_OUT(23, 3, 3, 0);
    TP_OUT(24, 3, 3, 2);
    TP_OUT(25, 3, 4, 1);
    TP_OUT(26, 3, 4, 3);

#pragma unroll
    for (int k = 0; k < 16; ++k) tv_w[q * 17 + k] = tv[k];
  }

  // ---- phase 3: out = s + tv[row], single store (same wave produced tv) ----
  if (ok) {
#pragma unroll
    for (int k = 0; k < 16; ++k) {
      const float t = tv_w[e16 * 17 + k];
      float4 o;
      o.x = s[k].x + t;
      o.y = s[k].y + t;
      o.z = s[k].z + t;
      o.w = s[k].w + t;
      o4[base + 4 * k] = o;
    }
  }
}

extern "C" void kernel_launch(void* const* d_in, const int* in_sizes, int n_in,
                              void* d_out, int out_size, void* d_ws, size_t ws_size,
                              hipStream_t stream) {
  const float4* x4 = (const float4*)d_in[0];
  const float4* y4 = (const float4*)d_in[1];
  const float* w1p = (const float*)d_in[2];
  const float* w21p = (const float*)d_in[3];
  const float* w22p = (const float*)d_in[4];
  float4* o4 = (float4*)d_out;

  const int E = in_sizes[0] / 256;          // (E, 16, 16) fp32
  const int block = 256;                    // 4 autonomous waves = 64 edges
  const int grid = (E + 63) / 64;

  cg2_v9<<<grid, block, 0, stream>>>(x4, y4, w1p, w21p, w22p, o4, E);
}

// Round 9
// 157.524 us; speedup vs baseline: 1.9290x; 1.1769x over previous
//
#include <hip/hip_runtime.h>

// ---------------------------------------------------------------------------
// Compile-time Clebsch-Gordan / real-basis Wigner-3j generation (exact port of
// the Python reference: _cg_coef, _su2_cg, _q, _w3j, normalization, pw).
// ---------------------------------------------------------------------------

struct W3JT { double v[9][9][9]; };

constexpr double dfact(int n) { double r = 1.0; for (int i = 2; i <= n; ++i) r *= (double)i; return r; }

constexpr double csqrt(double x) {
  if (x <= 0.0) return 0.0;
  double g = x > 1.0 ? x : 1.0;
  for (int i = 0; i < 80; ++i) g = 0.5 * (g + x / g);
  return g;
}

constexpr double cg_coef(int j1, int m1, int j2, int m2, int j3, int m3) {
  if (m1 + m2 != m3) return 0.0;
  int vmin = 0;
  if (j2 - j3 - m1 > vmin) vmin = j2 - j3 - m1;
  if (j1 - j3 + m2 > vmin) vmin = j1 - j3 + m2;
  int vmax = j1 + j2 - j3;
  if (j1 - m1 < vmax) vmax = j1 - m1;
  if (j2 + m2 < vmax) vmax = j2 + m2;
  double pref = csqrt((2.0 * j3 + 1.0) * dfact(j3 + j1 - j2) * dfact(j3 - j1 + j2) * dfact(j1 + j2 - j3) / dfact(j1 + j2 + j3 + 1));
  pref *= csqrt(dfact(j3 + m3) * dfact(j3 - m3) * dfact(j1 + m1) * dfact(j1 - m1) * dfact(j2 + m2) * dfact(j2 - m2));
  double s = 0.0;
  for (int v = vmin; v <= vmax; ++v) {
    double t = 1.0 / (dfact(v) * dfact(j1 + j2 - j3 - v) * dfact(j1 - m1 - v) * dfact(j2 + m2 - v) * dfact(j3 - j2 + m1 + v) * dfact(j3 - j1 - m2 + v));
    s += (v & 1) ? -t : t;
  }
  return pref * s;
}

// Nonzero rows of column `col` of the complex->real change-of-basis matrix
// q(l) (each column has <=2 nonzeros), with the (-i)^l phase applied.
struct QCol { int n; int row[2]; double re[2]; double im[2]; };

constexpr QCol qcol(int l, int col) {
  QCol q{};
  const int lm = l & 3;
  const double pr = (lm == 0) ? 1.0 : (lm == 2) ? -1.0 : 0.0;   // Re((-i)^l)
  const double pi = (lm == 1) ? -1.0 : (lm == 3) ? 1.0 : 0.0;   // Im((-i)^l)
  const int mu = col - l;
  const int am = mu < 0 ? -mu : mu;
  const double is2 = 0.70710678118654752440;
  if (mu == 0) {
    q.n = 1; q.row[0] = l;
    q.re[0] = pr; q.im[0] = pi;
  } else {
    const double s = (am & 1) ? -1.0 : 1.0;   // (-1)^|m|
    double a0 = 0.0, b0 = 0.0, a1 = 0.0, b1 = 0.0;
    if (mu > 0) { a0 = is2; b0 = 0.0;  a1 = s * is2; b1 = 0.0; }      // col l+|m|
    else        { a0 = 0.0; b0 = -is2; a1 = 0.0;     b1 = s * is2; }  // col l-|m|
    q.n = 2;
    q.row[0] = l - am; q.row[1] = l + am;
    q.re[0] = a0 * pr - b0 * pi; q.im[0] = a0 * pi + b0 * pr;
    q.re[1] = a1 * pr - b1 * pi; q.im[1] = a1 * pi + b1 * pr;
  }
  return q;
}

constexpr W3JT make_w3j(int l1, int l2, int l3) {
  W3JT R{};
  double C[9][9][9]{};
  for (int m1 = -l1; m1 <= l1; ++m1)
    for (int m2 = -l2; m2 <= l2; ++m2) {
      int m3 = m1 + m2;
      if (m3 >= -l3 && m3 <= l3)
        C[l1 + m1][l2 + m2][l3 + m3] = cg_coef(l1, m1, l2, m2, l3, m3);
    }
  // C_real[j][l][m] = Re( sum q1[i][j] q2[k][l] conj(q3[n][m]) C[i][k][n] )
  double nrm = 0.0;
  for (int j = 0; j < 2 * l1 + 1; ++j) {
    QCol q1 = qcol(l1, j);
    for (int l = 0; l < 2 * l2 + 1; ++l) {
      QCol q2 = qcol(l2, l);
      for (int m = 0; m < 2 * l3 + 1; ++m) {
        QCol q3 = qcol(l3, m);
        double re = 0.0;
        for (int a = 0; a < q1.n; ++a)
          for (int b = 0; b < q2.n; ++b)
            for (int c = 0; c < q3.n; ++c) {
              double cv = C[q1.row[a]][q2.row[b]][q3.row[c]];
              if (cv == 0.0) continue;
              double ar = q1.re[a], ai = q1.im[a];
              double br = q2.re[b], bi = q2.im[b];
              double cr = q3.re[c], ci = -q3.im[c];   // conj
              double abr = ar * br - ai * bi;
              double abi = ar * bi + ai * br;
              double prr = abr * cr - abi * ci;       // Re(triple product)
              re += prr * cv;
            }
        R.v[j][l][m] = re;
        nrm += re * re;
      }
    }
  }
  double n = csqrt(nrm);
  if (n > 0.0)
    for (int j = 0; j < 2 * l1 + 1; ++j)
      for (int l = 0; l < 2 * l2 + 1; ++l)
        for (int m = 0; m < 2 * l3 + 1; ++m)
          R.v[j][l][m] /= n;
  return R;
}

// instruction counts per output-l (verified against the reference enumeration)
// INS1  = instructions(3,3,4): c-counts {4,6,7,6,4}
// INS21 = instructions(3,4,3): c-counts {4,7,8,8}   (INS22 identical)
constexpr int CNT1[5] = {4, 6, 7, 6, 4};
constexpr int CNT2[4] = {4, 7, 8, 8};

#define NZCHK(V) ((V) > 1e-12 || (V) < -1e-12)

// mid[c*c+k] += w1[IDX] * pw * sum_ij W3J[i][j][k] * xm[a*a+i] * ym[b*b+j]
#define TP_MID(IDX, A, B, C) do { \
  constexpr W3JT T = make_w3j(A, B, C); \
  constexpr double PW = csqrt((2.0 * (C) + 1.0) / (double)CNT1[(C)]); \
  const float wi = w1p[IDX]; \
  float u[2 * (A) + 1]; \
  _Pragma("unroll") for (int i = 0; i < 2 * (A) + 1; ++i) u[i] = wi * xm[(A) * (A) + i]; \
  _Pragma("unroll") for (int i = 0; i < 2 * (A) + 1; ++i) { \
    _Pragma("unroll") for (int j = 0; j < 2 * (B) + 1; ++j) { \
      const float p_ = u[i] * ym[(B) * (B) + j]; \
      _Pragma("unroll") for (int k = 0; k < 2 * (C) + 1; ++k) { \
        if (NZCHK(T.v[i][j][k])) \
          mid[(C) * (C) + k] = __builtin_fmaf((float)(T.v[i][j][k] * PW), p_, mid[(C) * (C) + k]); \
      } \
    } \
  } \
} while (0)

// tv[c*c+k] += pw * sum_ij W3J[i][j][k] * (w21[IDX]*xm_i + w22[IDX]*ym_i) * mid_j
#define TP_OUT(IDX, A, B, C) do { \
  constexpr W3JT T = make_w3j(A, B, C); \
  constexpr double PW = csqrt((2.0 * (C) + 1.0) / (double)CNT2[(C)]); \
  const float wa = w21p[IDX]; \
  const float wb = w22p[IDX]; \
  float u[2 * (A) + 1]; \
  _Pragma("unroll") for (int i = 0; i < 2 * (A) + 1; ++i) \
    u[i] = wa * xm[(A) * (A) + i] + wb * ym[(A) * (A) + i]; \
  _Pragma("unroll") for (int i = 0; i < 2 * (A) + 1; ++i) { \
    _Pragma("unroll") for (int j = 0; j < 2 * (B) + 1; ++j) { \
      const float p_ = u[i] * mid[(B) * (B) + j]; \
      _Pragma("unroll") for (int k = 0; k < 2 * (C) + 1; ++k) { \
        if (NZCHK(T.v[i][j][k])) \
          tv[(C) * (C) + k] = __builtin_fmaf((float)(T.v[i][j][k] * PW), p_, tv[(C) * (C) + k]); \
      } \
    } \
  } \
} while (0)

// ---------------------------------------------------------------------------
// v11: v6 structure + grid-stride loop (Guideline 11). Grid capped at 1024
// blocks (4 blocks/CU = the VGPR residency cap); each block processes ~3
// tiles of 64 edges. One dispatch ramp instead of 3125 short-lived blocks:
// residency climbs to the cap and stays, barriers of different blocks
// interleave, the chain of one block overlaps the load phase of others.
//  phase 1: coalesced loads (4 lanes/edge), s=x+y in regs,
//           quad-butterfly row means -> LDS.
//  phase 2: wave 0: lane q runs the constant-folded chain for edge q, tv->LDS.
//  phase 3: out = s + tv[row], single store.
// Cross-iteration LDS hazard check: after barrier 2, a fast wave writing
// lmx(i+1) never aliases a slow wave reading ltv(i); barrier counts match
// across all waves of a block (loop bound depends only on blockIdx).
// ---------------------------------------------------------------------------
__global__ __launch_bounds__(256) void cg2_v11(
    const float4* __restrict__ x4, const float4* __restrict__ y4,
    const float* __restrict__ w1p, const float* __restrict__ w21p,
    const float* __restrict__ w22p, float4* __restrict__ o4, int E)
{
  __shared__ float lmx[64 * 32];   // xm/ym per edge-in-block, rotate-swizzled
  __shared__ float ltv[64 * 16];   // tv per edge-in-block, rotate-swizzled

  const int eL = threadIdx.x >> 2;        // edge-in-block 0..63
  const int g  = threadIdx.x & 3;         // quad lane
  const int tiles = (E + 63) >> 6;

  for (int tile = blockIdx.x; tile < tiles; tile += gridDim.x) {
    const int e = tile * 64 + eL;
    const bool ok = (e < E);
    const int base = e * 64 + g;          // float4 index

    // ---- phase 1: loads, s=x+y in regs, row partials ----
    float4 s[16];
    float px[16], py[16];
    if (ok) {
#pragma unroll
      for (int k = 0; k < 16; ++k) {
        const float4 xv = x4[base + 4 * k];
        const float4 yv = y4[base + 4 * k];
        s[k].x = xv.x + yv.x; s[k].y = xv.y + yv.y;
        s[k].z = xv.z + yv.z; s[k].w = xv.w + yv.w;
        px[k] = (xv.x + xv.y) + (xv.z + xv.w);
        py[k] = (yv.x + yv.y) + (yv.z + yv.w);
      }
    } else {
#pragma unroll
      for (int k = 0; k < 16; ++k) { px[k] = 0.f; py[k] = 0.f; }
    }

    // quad butterflies -> full row means (replicated in all 4 lanes)
#pragma unroll
    for (int k = 0; k < 16; ++k) {
      float rx = px[k] + __shfl_xor(px[k], 1);
      rx += __shfl_xor(rx, 2);
      float ry = py[k] + __shfl_xor(py[k], 1);
      ry += __shfl_xor(ry, 2);
      px[k] = rx * (1.0f / 16.0f);
      py[k] = ry * (1.0f / 16.0f);
    }

    // write xm (slots 0..15) and ym (slots 16..31): thread g covers j=4g..4g+3
    if (ok) {
#pragma unroll
      for (int u = 0; u < 4; ++u) {
        const int j = 4 * g + u;
        lmx[eL * 32 + ((j + eL) & 31)]      = px[j];
        lmx[eL * 32 + ((16 + j + eL) & 31)] = py[j];
      }
    }
    __syncthreads();

    // ---- phase 2: wave 0 runs the chain, one edge per lane ----
    if (threadIdx.x < 64) {
      const int q = threadIdx.x;
      const bool ok2 = (tile * 64 + q < E);
      float xm[16], ym[16];
#pragma unroll
      for (int j = 0; j < 16; ++j) xm[j] = lmx[q * 32 + ((j + q) & 31)];
#pragma unroll
      for (int j = 0; j < 16; ++j) ym[j] = lmx[q * 32 + ((16 + j + q) & 31)];

      float mid[25];
#pragma unroll
      for (int k = 0; k < 25; ++k) mid[k] = 0.f;

      // INS1 = instructions(3,3,4), reference order
      TP_MID( 0, 0, 0, 0);
      TP_MID( 1, 0, 1, 1);
      TP_MID( 2, 0, 2, 2);
      TP_MID( 3, 0, 3, 3);
      TP_MID( 4, 1, 0, 1);
      TP_MID( 5, 1, 1, 0);
      TP_MID( 6, 1, 1, 2);
      TP_MID( 7, 1, 2, 1);
      TP_MID( 8, 1, 2, 3);
      TP_MID( 9, 1, 3, 2);
      TP_MID(10, 1, 3, 4);
      TP_MID(11, 2, 0, 2);
      TP_MID(12, 2, 1, 1);
      TP_MID(13, 2, 1, 3);
      TP_MID(14, 2, 2, 0);
      TP_MID(15, 2, 2, 2);
      TP_MID(16, 2, 2, 4);
      TP_MID(17, 2, 3, 1);
      TP_MID(18, 2, 3, 3);
      TP_MID(19, 3, 0, 3);
      TP_MID(20, 3, 1, 2);
      TP_MID(21, 3, 1, 4);
      TP_MID(22, 3, 2, 1);
      TP_MID(23, 3, 2, 3);
      TP_MID(24, 3, 3, 0);
      TP_MID(25, 3, 3, 2);
      TP_MID(26, 3, 3, 4);

      float tv[16];
#pragma unroll
      for (int k = 0; k < 16; ++k) tv[k] = 0.f;

      // INS21 == INS22 = instructions(3,4,3); fused via u = w21*xm + w22*ym
      TP_OUT( 0, 0, 0, 0);
      TP_OUT( 1, 0, 1, 1);
      TP_OUT( 2, 0, 2, 2);
      TP_OUT( 3, 0, 3, 3);
      TP_OUT( 4, 1, 0, 1);
      TP_OUT( 5, 1, 1, 0);
      TP_OUT( 6, 1, 1, 2);
      TP_OUT( 7, 1, 2, 1);
      TP_OUT( 8, 1, 2, 3);
      TP_OUT( 9, 1, 3, 2);
      TP_OUT(10, 1, 4, 3);
      TP_OUT(11, 2, 0, 2);
      TP_OUT(12, 2, 1, 1);
      TP_OUT(13, 2, 1, 3);
      TP_OUT(14, 2, 2, 0);
      TP_OUT(15, 2, 2, 2);
      TP_OUT(16, 2, 3, 1);
      TP_OUT(17, 2, 3, 3);
      TP_OUT(18, 2, 4, 2);
      TP_OUT(19, 3, 0, 3);
      TP_OUT(20, 3, 1, 2);
      TP_OUT(21, 3, 2, 1);
      TP_OUT(22, 3, 2, 3);
      TP_OUT(23, 3, 3, 0);
      TP_OUT(24, 3, 3, 2);
      TP_OUT(25, 3, 4, 1);
      TP_OUT(26, 3, 4, 3);

      if (ok2) {
#pragma unroll
        for (int k = 0; k < 16; ++k) ltv[q * 16 + ((k + q) & 15)] = tv[k];
      }
    }
    __syncthreads();

    // ---- phase 3: out = s + tv[row], single store ----
    if (ok) {
#pragma unroll
      for (int k = 0; k < 16; ++k) {
        const float t = ltv[eL * 16 + ((k + eL) & 15)];
        float4 o;
        o.x = s[k].x + t;
        o.y = s[k].y + t;
        o.z = s[k].z + t;
        o.w = s[k].w + t;
        o4[base + 4 * k] = o;
      }
    }
  }
}

extern "C" void kernel_launch(void* const* d_in, const int* in_sizes, int n_in,
                              void* d_out, int out_size, void* d_ws, size_t ws_size,
                              hipStream_t stream) {
  const float4* x4 = (const float4*)d_in[0];
  const float4* y4 = (const float4*)d_in[1];
  const float* w1p = (const float*)d_in[2];
  const float* w21p = (const float*)d_in[3];
  const float* w22p = (const float*)d_in[4];
  float4* o4 = (float4*)d_out;

  const int E = in_sizes[0] / 256;          // (E, 16, 16) fp32
  const int block = 256;                    // 64 edges per tile
  const int tiles = (E + 63) / 64;          // 3125
  const int grid = tiles < 1024 ? tiles : 1024;  // 4 blocks/CU, grid-stride

  cg2_v11<<<grid, block, 0, stream>>>(x4, y4, w1p, w21p, w22p, o4, E);
}